// Round 7
// baseline (169.954 us; speedup 1.0000x reference)
//
#include <hip/hip_runtime.h>
#include <stdint.h>

#define BATCH 4096
#define DDIM  768
#define EDIM  512
#define NSPLIT 32
#define LOG2E 1.44269504088896340736f

using short8  = __attribute__((ext_vector_type(8))) short;
using float4v = __attribute__((ext_vector_type(4))) float;

__device__ __forceinline__ unsigned short f2bf(float x) {
    union { float f; uint32_t u; } v; v.f = x;
    uint32_t u = v.u;
    u += 0x7FFFu + ((u >> 16) & 1u);   // round-to-nearest-even
    return (unsigned short)(u >> 16);
}
__device__ __forceinline__ float bf2f(unsigned short h) {
    union { uint32_t u; float f; } v; v.u = ((uint32_t)h) << 16;
    return v.f;
}

// async global->LDS, 16B per lane; LDS dst must be wave-uniform base + lane*16
__device__ __forceinline__ void gl2lds16(const void* g, void* l) {
    __builtin_amdgcn_global_load_lds(
        (const __attribute__((address_space(1))) void*)g,
        (__attribute__((address_space(3))) void*)l, 16, 0, 0);
}

// ---------------- prep: fp32->bf16 casts + both W transposes, one launch ----------------
// blocks [0,6144): cvt (img then txt); blocks [6144,6912): transpose (W_img then W_txt)
__global__ void prep(const float* __restrict__ images, const float* __restrict__ texts,
                     const float* __restrict__ Wa, const float* __restrict__ Wb,
                     unsigned short* __restrict__ img_bf, unsigned short* __restrict__ txt_bf,
                     unsigned short* __restrict__ Ta, unsigned short* __restrict__ Tb) {
    __shared__ float tile[32][33];
    int b = blockIdx.x;
    int tid = threadIdx.x;
    if (b < 6144) {
        int which = b >= 3072;
        const float* in = which ? texts : images;
        unsigned short* out = which ? txt_bf : img_bf;
        int i = (which ? b - 3072 : b) * 256 + tid;
        float4 v = ((const float4*)in)[i];
        ushort4 o;
        o.x = f2bf(v.x); o.y = f2bf(v.y); o.z = f2bf(v.z); o.w = f2bf(v.w);
        ((ushort4*)out)[i] = o;
    } else {
        int z = b - 6144;                  // 0..767
        int which = z >= 384;
        int rem = which ? z - 384 : z;     // 0..383 = 16 (n) x 24 (k)
        const float* W = which ? Wb : Wa;
        unsigned short* Wt = which ? Tb : Ta;
        int n0 = (rem & 15) * 32, k0 = (rem >> 4) * 32;
        for (int p = 0; p < 4; ++p) {
            int e = tid + p * 256; int lr = e >> 5, lc = e & 31;
            tile[lc][lr] = W[(size_t)(k0 + lr) * EDIM + n0 + lc];
        }
        __syncthreads();
        for (int p = 0; p < 4; ++p) {
            int e = tid + p * 256; int lr = e >> 5, lc = e & 31;
            Wt[(size_t)(n0 + lr) * DDIM + k0 + lc] = f2bf(tile[lr][lc]);
        }
    }
}

// ---------------- fused NT GEMM (both modalities): Cbf16[4096x512] = A @ W^T ----------------
// grid (32, 8, 2); block 256 = 4 waves; tile 128x64, wave = 32 rows x 64 cols (2 row-groups)
__global__ __launch_bounds__(256) void gemm_nt(const unsigned short* __restrict__ Aimg,
                                               const unsigned short* __restrict__ Atxt,
                                               const unsigned short* __restrict__ Bimg,
                                               const unsigned short* __restrict__ Btxt,
                                               unsigned short* __restrict__ Cimg,
                                               unsigned short* __restrict__ Ctxt) {
    const unsigned short* A  = blockIdx.z ? Atxt : Aimg;
    const unsigned short* Bm = blockIdx.z ? Btxt : Bimg;
    unsigned short* C        = blockIdx.z ? Ctxt : Cimg;
    __shared__ __align__(16) unsigned short As[2 * 128 * 32];  // 16 KB
    __shared__ __align__(16) unsigned short Bs[2 * 64 * 32];   //  8 KB
    int tid = threadIdx.x;
    int wave = tid >> 6, lane = tid & 63;
    int q = lane >> 4, r = lane & 15;
    int m0 = blockIdx.x * 128, n0 = blockIdx.y * 64;
    int sw = (r >> 1) & 3;

    const unsigned short* gsA[4];
    unsigned short* lsA[4];
    for (int i = 0; i < 4; ++i) {
        int u = i * 256 + tid;
        int kc2 = u >> 9, row = (u >> 2) & 127, kq = u & 3;
        int kq2 = kq ^ ((row >> 1) & 3);
        gsA[i] = &A[(size_t)(m0 + row) * DDIM + kc2 * 32 + kq2 * 8];
        lsA[i] = &As[u * 8];
    }
    const unsigned short* gsB[2];
    unsigned short* lsB[2];
    for (int i = 0; i < 2; ++i) {
        int u = i * 256 + tid;
        int kc2 = u >> 8, row = (u >> 2) & 63, kq = u & 3;
        int kq2 = kq ^ ((row >> 1) & 3);
        gsB[i] = &Bm[(size_t)(n0 + row) * DDIM + kc2 * 32 + kq2 * 8];
        lsB[i] = &Bs[u * 8];
    }

    float4v acc[2][4];
    for (int a = 0; a < 2; ++a)
        for (int t = 0; t < 4; ++t) acc[a][t] = (float4v){0.f, 0.f, 0.f, 0.f};

    for (int it = 0; it < DDIM / 64; ++it) {
        int k0 = it * 64;
        __syncthreads();
        for (int i = 0; i < 4; ++i) gl2lds16(gsA[i] + k0, lsA[i]);
        for (int i = 0; i < 2; ++i) gl2lds16(gsB[i] + k0, lsB[i]);
        __syncthreads();
        for (int kc2 = 0; kc2 < 2; ++kc2) {
            short8 a0 = *(const short8*)&As[kc2 * 4096 + (wave * 32 + r) * 32 + (q ^ sw) * 8];
            short8 a1 = *(const short8*)&As[kc2 * 4096 + (wave * 32 + 16 + r) * 32 + (q ^ sw) * 8];
            for (int t = 0; t < 4; ++t) {
                short8 b = *(const short8*)&Bs[kc2 * 2048 + (t * 16 + r) * 32 + (q ^ sw) * 8];
                acc[0][t] = __builtin_amdgcn_mfma_f32_16x16x32_bf16(a0, b, acc[0][t], 0, 0, 0);
                acc[1][t] = __builtin_amdgcn_mfma_f32_16x16x32_bf16(a1, b, acc[1][t], 0, 0, 0);
            }
        }
    }
    for (int rg = 0; rg < 2; ++rg)
        for (int t = 0; t < 4; ++t)
            for (int g = 0; g < 4; ++g)
                C[(size_t)(m0 + wave * 32 + rg * 16 + q * 4 + g) * EDIM + n0 + t * 16 + r] =
                    f2bf(acc[rg][t][g]);
}

// ---------------- in-place row L2-normalize of bf16 projections (both) ----------------
__global__ void norm_rows(unsigned short* __restrict__ Pa, unsigned short* __restrict__ Pb) {
    unsigned short* P = blockIdx.y ? Pb : Pa;
    int wave = threadIdx.x >> 6, lane = threadIdx.x & 63;
    int row = blockIdx.x * 4 + wave;
    unsigned short* p = &P[(size_t)row * 512 + lane * 8];
    union { unsigned short us[8]; uint4 u4; } v;
    v.u4 = *(const uint4*)p;
    float f[8], s = 0.f;
    for (int j = 0; j < 8; ++j) { f[j] = bf2f(v.us[j]); s += f[j] * f[j]; }
    for (int off = 1; off < 64; off <<= 1) s += __shfl_xor(s, off);
    float rn = rsqrtf(s);
    for (int j = 0; j < 8; ++j) v.us[j] = f2bf(f[j] * rn);
    *(uint4*)p = v.u4;
}

// ---------------- raw dot: tvals[i] = dot(img_n[i], txt_n[labels[i]]) ----------------
__global__ void tdot(const unsigned short* __restrict__ img, const unsigned short* __restrict__ txt,
                     const int* __restrict__ labels, float* __restrict__ tout) {
    int wave = threadIdx.x >> 6, lane = threadIdx.x & 63;
    int row = blockIdx.x * 4 + wave;
    int lab = labels[row];
    union { unsigned short us[8]; uint4 u4; } a, b;
    a.u4 = *(const uint4*)&img[(size_t)row * 512 + lane * 8];
    b.u4 = *(const uint4*)&txt[(size_t)lab * 512 + lane * 8];
    float s = 0.f;
    for (int j = 0; j < 8; ++j) s += bf2f(a.us[j]) * bf2f(b.us[j]);
    for (int off = 1; off < 64; off <<= 1) s += __shfl_xor(s, off);
    if (lane == 0) tout[row] = s;
}

// ---------------- fused logits + fixed-max softmax sums + masked denom ----------------
// R4's kernel shape (A reg-resident 32 rows/wave -> 0.5 ds_reads/MFMA, long 32 KB
// staging rounds) at R3's grid size: NSPLIT=32, grid (32,32)=1024 blocks (~3 blocks/CU).
// Block: 128 rows x 128 cols; wave: 32 rows x 128 cols; 4 staging rounds/block.
// Fixed max M = alpha (|logit| <= alpha, L2-normalized inputs) -> per-lane accumulation.
// NOTE: no min-waves in launch_bounds (R2: (256,4) capped VGPR at 64 -> spilled af[]).
__global__ __launch_bounds__(256) void flash_pass(
    const unsigned short* __restrict__ img, const unsigned short* __restrict__ txt,
    const int* __restrict__ labels, const float* __restrict__ tvals,
    const float* __restrict__ ls,
    float* __restrict__ lP, float* __restrict__ dP) {
    __shared__ __align__(16) unsigned short Bs[8 * 64 * 32];  // 32 KB
    int tid = threadIdx.x;
    int wave = tid >> 6, lane = tid & 63;
    int q = lane >> 4, r = lane & 15;
    int row0 = blockIdx.x * 128 + wave * 32;
    int split = blockIdx.y;
    float c1 = expf(ls[0]) * LOG2E;    // p = exp2(c1*(cos - 1)) = e^{s - M}, M = alpha

    int srow = tid >> 2, skp = tid & 3;
    int skp2 = skp ^ ((srow >> 1) & 3);
    int sw = (r >> 1) & 3;

    // A fragments: 2 row-groups x 16 k-chunks, register-resident (128 VGPRs; R4: held, no spill)
    short8 af[2][16];
    for (int rg = 0; rg < 2; ++rg)
        for (int kc = 0; kc < 16; ++kc)
            af[rg][kc] = *(const short8*)&img[(size_t)(row0 + rg * 16 + r) * 512 + kc * 32 + q * 8];

    int labr[8]; float tr[8];
    for (int rg = 0; rg < 2; ++rg)
        for (int g = 0; g < 4; ++g) {
            int rw = row0 + rg * 16 + q * 4 + g;
            labr[rg * 4 + g] = labels[rw];
            tr[rg * 4 + g] = tvals[rw];
        }
    float l[8] = {0.f}, d[8] = {0.f};

    for (int ct = 0; ct < 2; ++ct) {
        int colbase = split * 128 + ct * 64;
        const unsigned short* gB = &txt[(size_t)(colbase + srow) * 512 + skp2 * 8];
        float4v acc[2][4];
        for (int rg = 0; rg < 2; ++rg)
            for (int t = 0; t < 4; ++t) acc[rg][t] = (float4v){0.f, 0.f, 0.f, 0.f};
        for (int h = 0; h < 2; ++h) {
            __syncthreads();
            for (int i = 0; i < 8; ++i)
                gl2lds16(gB + h * 256 + i * 32, &Bs[i * 2048 + tid * 8]);
            __syncthreads();
            for (int kc = 0; kc < 8; ++kc) {
                short8 a0 = af[0][h * 8 + kc];
                short8 a1 = af[1][h * 8 + kc];
                for (int t = 0; t < 4; ++t) {
                    short8 bf = *(const short8*)&Bs[(kc * 64 + t * 16 + r) * 32 + (q ^ sw) * 8];
                    acc[0][t] = __builtin_amdgcn_mfma_f32_16x16x32_bf16(a0, bf, acc[0][t], 0, 0, 0);
                    acc[1][t] = __builtin_amdgcn_mfma_f32_16x16x32_bf16(a1, bf, acc[1][t], 0, 0, 0);
                }
            }
        }
        for (int t = 0; t < 4; ++t) {
            int lc = labels[colbase + t * 16 + r];
            for (int rg = 0; rg < 2; ++rg)
                for (int g = 0; g < 4; ++g) {
                    float a = acc[rg][t][g];
                    float p = exp2f(fmaf(a, c1, -c1));
                    int ix = rg * 4 + g;
                    l[ix] += p;
                    d[ix] += ((a > tr[ix]) && (lc != labr[ix])) ? p : 0.f;
                }
        }
    }
    for (int ix = 0; ix < 8; ++ix) {
        float lv = l[ix], dv = d[ix];
        for (int off = 1; off < 16; off <<= 1) {
            lv += __shfl_xor(lv, off);
            dv += __shfl_xor(dv, off);
        }
        if (r == 0) {
            int rw = row0 + (ix >> 2) * 16 + q * 4 + (ix & 3);
            lP[(size_t)split * BATCH + rw] = lv;
            dP[(size_t)split * BATCH + rw] = dv;
        }
    }
}

// ---------------- merge splits + per-row losses + global sum (atomic) ----------------
__global__ void combine(const float* __restrict__ lP, const float* __restrict__ dP,
                        const float* __restrict__ tvals, const float* __restrict__ ls,
                        float* __restrict__ out) {
    int row = blockIdx.x * 256 + threadIdx.x;
    float alpha = expf(ls[0]);
    float L = 0.f, D = 0.f;
    for (int s = 0; s < NSPLIT; ++s) {
        L += lP[(size_t)s * BATCH + row];
        D += dP[(size_t)s * BATCH + row];
    }
    float tm = alpha * (tvals[row] - 1.0f);   // t - M, with M = alpha
    float clip = logf(L) - tm;
    float py = expf(tm) / L;
    float cmp = (D > 0.f) ? py / (D / L + 1e-10f) : 0.f;
    float v = clip + cmp;
    for (int off = 1; off < 64; off <<= 1) v += __shfl_xor(v, off);
    __shared__ float w4[4];
    int wave = threadIdx.x >> 6, lane = threadIdx.x & 63;
    if (lane == 0) w4[wave] = v;
    __syncthreads();
    if (threadIdx.x == 0)
        atomicAdd(out, (w4[0] + w4[1] + w4[2] + w4[3]) * (1.0f / BATCH));
}

extern "C" void kernel_launch(void* const* d_in, const int* in_sizes, int n_in,
                              void* d_out, int out_size, void* d_ws, size_t ws_size,
                              hipStream_t stream) {
    const float* images = (const float*)d_in[0];
    const float* texts  = (const float*)d_in[1];
    const int*   labels = (const int*)d_in[2];
    const float* W_img  = (const float*)d_in[3];
    const float* W_txt  = (const float*)d_in[4];
    const float* lscale = (const float*)d_in[5];
    float* out = (float*)d_out;

    char* ws = (char*)d_ws;
    unsigned short* img_bf = (unsigned short*)(ws + 0);           // 6,291,456 B
    unsigned short* txt_bf = (unsigned short*)(ws + 6291456);     // 6,291,456 B
    unsigned short* wt_img = (unsigned short*)(ws + 12582912);    //   786,432 B
    unsigned short* wt_txt = (unsigned short*)(ws + 13369344);    //   786,432 B
    unsigned short* proj_i = (unsigned short*)(ws + 14155776);    // 4,194,304 B (bf16 img_n)
    unsigned short* proj_t = (unsigned short*)(ws + 18350080);    // 4,194,304 B (bf16 txt_n)
    // aliased over dead img_bf region (written only after the fused gemm):
    float*          lP     = (float*)(ws + 0);                    //   524,288 B
    float*          dP     = (float*)(ws + 524288);               //   524,288 B
    float*          tvals  = (float*)(ws + 1048576);              //    16,384 B

    hipMemsetAsync(out, 0, sizeof(float), stream);
    prep<<<6912, 256, 0, stream>>>(images, texts, W_img, W_txt, img_bf, txt_bf, wt_img, wt_txt);
    gemm_nt<<<dim3(BATCH / 128, EDIM / 64, 2), 256, 0, stream>>>(img_bf, txt_bf, wt_img, wt_txt,
                                                                 proj_i, proj_t);
    norm_rows<<<dim3(BATCH / 4, 2), 256, 0, stream>>>(proj_i, proj_t);
    tdot<<<BATCH / 4, 256, 0, stream>>>(proj_i, proj_t, labels, tvals);
    flash_pass<<<dim3(BATCH / 128, NSPLIT), 256, 0, stream>>>(proj_i, proj_t, labels, tvals, lscale,
                                                              lP, dP);
    combine<<<16, 256, 0, stream>>>(lP, dP, tvals, lscale, out);
}

// Round 8
// 141.380 us; speedup vs baseline: 1.2021x; 1.2021x over previous
//
#include <hip/hip_runtime.h>
#include <stdint.h>

#define BATCH 4096
#define DDIM  768
#define EDIM  512
#define NSPLIT 64
#define LOG2E 1.44269504088896340736f

using short8  = __attribute__((ext_vector_type(8))) short;
using float4v = __attribute__((ext_vector_type(4))) float;

__device__ __forceinline__ unsigned short f2bf(float x) {
    union { float f; uint32_t u; } v; v.f = x;
    uint32_t u = v.u;
    u += 0x7FFFu + ((u >> 16) & 1u);   // round-to-nearest-even
    return (unsigned short)(u >> 16);
}
__device__ __forceinline__ float bf2f(unsigned short h) {
    union { uint32_t u; float f; } v; v.u = ((uint32_t)h) << 16;
    return v.f;
}

// async global->LDS, 16B per lane; LDS dst must be wave-uniform base + lane*16
__device__ __forceinline__ void gl2lds16(const void* g, void* l) {
    __builtin_amdgcn_global_load_lds(
        (const __attribute__((address_space(1))) void*)g,
        (__attribute__((address_space(3))) void*)l, 16, 0, 0);
}

// ---------------- prep: fp32->bf16 casts + both W transposes, one launch ----------------
__global__ void prep(const float* __restrict__ images, const float* __restrict__ texts,
                     const float* __restrict__ Wa, const float* __restrict__ Wb,
                     unsigned short* __restrict__ img_bf, unsigned short* __restrict__ txt_bf,
                     unsigned short* __restrict__ Ta, unsigned short* __restrict__ Tb) {
    __shared__ float tile[32][33];
    int b = blockIdx.x;
    int tid = threadIdx.x;
    if (b < 6144) {
        int which = b >= 3072;
        const float* in = which ? texts : images;
        unsigned short* out = which ? txt_bf : img_bf;
        int i = (which ? b - 3072 : b) * 256 + tid;
        float4 v = ((const float4*)in)[i];
        ushort4 o;
        o.x = f2bf(v.x); o.y = f2bf(v.y); o.z = f2bf(v.z); o.w = f2bf(v.w);
        ((ushort4*)out)[i] = o;
    } else {
        int z = b - 6144;                  // 0..767
        int which = z >= 384;
        int rem = which ? z - 384 : z;     // 0..383 = 16 (n) x 24 (k)
        const float* W = which ? Wb : Wa;
        unsigned short* Wt = which ? Tb : Ta;
        int n0 = (rem & 15) * 32, k0 = (rem >> 4) * 32;
        for (int p = 0; p < 4; ++p) {
            int e = tid + p * 256; int lr = e >> 5, lc = e & 31;
            tile[lc][lr] = W[(size_t)(k0 + lr) * EDIM + n0 + lc];
        }
        __syncthreads();
        for (int p = 0; p < 4; ++p) {
            int e = tid + p * 256; int lr = e >> 5, lc = e & 31;
            Wt[(size_t)(n0 + lr) * DDIM + k0 + lc] = f2bf(tile[lr][lc]);
        }
    }
}

// ---------------- fused NT GEMM (both modalities): Cbf16[4096x512] = A @ W^T ----------------
// grid (32, 8, 2); block 256 = 4 waves; tile 128x64, wave = 32 rows x 64 cols (2 row-groups)
__global__ __launch_bounds__(256) void gemm_nt(const unsigned short* __restrict__ Aimg,
                                               const unsigned short* __restrict__ Atxt,
                                               const unsigned short* __restrict__ Bimg,
                                               const unsigned short* __restrict__ Btxt,
                                               unsigned short* __restrict__ Cimg,
                                               unsigned short* __restrict__ Ctxt) {
    const unsigned short* A  = blockIdx.z ? Atxt : Aimg;
    const unsigned short* Bm = blockIdx.z ? Btxt : Bimg;
    unsigned short* C        = blockIdx.z ? Ctxt : Cimg;
    __shared__ __align__(16) unsigned short As[2 * 128 * 32];  // 16 KB
    __shared__ __align__(16) unsigned short Bs[2 * 64 * 32];   //  8 KB
    int tid = threadIdx.x;
    int wave = tid >> 6, lane = tid & 63;
    int q = lane >> 4, r = lane & 15;
    int m0 = blockIdx.x * 128, n0 = blockIdx.y * 64;
    int sw = (r >> 1) & 3;

    const unsigned short* gsA[4];
    unsigned short* lsA[4];
    for (int i = 0; i < 4; ++i) {
        int u = i * 256 + tid;
        int kc2 = u >> 9, row = (u >> 2) & 127, kq = u & 3;
        int kq2 = kq ^ ((row >> 1) & 3);
        gsA[i] = &A[(size_t)(m0 + row) * DDIM + kc2 * 32 + kq2 * 8];
        lsA[i] = &As[u * 8];
    }
    const unsigned short* gsB[2];
    unsigned short* lsB[2];
    for (int i = 0; i < 2; ++i) {
        int u = i * 256 + tid;
        int kc2 = u >> 8, row = (u >> 2) & 63, kq = u & 3;
        int kq2 = kq ^ ((row >> 1) & 3);
        gsB[i] = &Bm[(size_t)(n0 + row) * DDIM + kc2 * 32 + kq2 * 8];
        lsB[i] = &Bs[u * 8];
    }

    float4v acc[2][4];
    for (int a = 0; a < 2; ++a)
        for (int t = 0; t < 4; ++t) acc[a][t] = (float4v){0.f, 0.f, 0.f, 0.f};

    for (int it = 0; it < DDIM / 64; ++it) {
        int k0 = it * 64;
        __syncthreads();
        for (int i = 0; i < 4; ++i) gl2lds16(gsA[i] + k0, lsA[i]);
        for (int i = 0; i < 2; ++i) gl2lds16(gsB[i] + k0, lsB[i]);
        __syncthreads();
        for (int kc2 = 0; kc2 < 2; ++kc2) {
            short8 a0 = *(const short8*)&As[kc2 * 4096 + (wave * 32 + r) * 32 + (q ^ sw) * 8];
            short8 a1 = *(const short8*)&As[kc2 * 4096 + (wave * 32 + 16 + r) * 32 + (q ^ sw) * 8];
            for (int t = 0; t < 4; ++t) {
                short8 b = *(const short8*)&Bs[kc2 * 2048 + (t * 16 + r) * 32 + (q ^ sw) * 8];
                acc[0][t] = __builtin_amdgcn_mfma_f32_16x16x32_bf16(a0, b, acc[0][t], 0, 0, 0);
                acc[1][t] = __builtin_amdgcn_mfma_f32_16x16x32_bf16(a1, b, acc[1][t], 0, 0, 0);
            }
        }
    }
    for (int rg = 0; rg < 2; ++rg)
        for (int t = 0; t < 4; ++t)
            for (int g = 0; g < 4; ++g)
                C[(size_t)(m0 + wave * 32 + rg * 16 + q * 4 + g) * EDIM + n0 + t * 16 + r] =
                    f2bf(acc[rg][t][g]);
}

// ---------------- in-place row L2-normalize of bf16 projections (both) ----------------
__global__ void norm_rows(unsigned short* __restrict__ Pa, unsigned short* __restrict__ Pb) {
    unsigned short* P = blockIdx.y ? Pb : Pa;
    int wave = threadIdx.x >> 6, lane = threadIdx.x & 63;
    int row = blockIdx.x * 4 + wave;
    unsigned short* p = &P[(size_t)row * 512 + lane * 8];
    union { unsigned short us[8]; uint4 u4; } v;
    v.u4 = *(const uint4*)p;
    float f[8], s = 0.f;
    for (int j = 0; j < 8; ++j) { f[j] = bf2f(v.us[j]); s += f[j] * f[j]; }
    for (int off = 1; off < 64; off <<= 1) s += __shfl_xor(s, off);
    float rn = rsqrtf(s);
    for (int j = 0; j < 8; ++j) v.us[j] = f2bf(f[j] * rn);
    *(uint4*)p = v.u4;
}

// ---------------- raw dot: tvals[i] = dot(img_n[i], txt_n[labels[i]]) ----------------
__global__ void tdot(const unsigned short* __restrict__ img, const unsigned short* __restrict__ txt,
                     const int* __restrict__ labels, float* __restrict__ tout) {
    int wave = threadIdx.x >> 6, lane = threadIdx.x & 63;
    int row = blockIdx.x * 4 + wave;
    int lab = labels[row];
    union { unsigned short us[8]; uint4 u4; } a, b;
    a.u4 = *(const uint4*)&img[(size_t)row * 512 + lane * 8];
    b.u4 = *(const uint4*)&txt[(size_t)lab * 512 + lane * 8];
    float s = 0.f;
    for (int j = 0; j < 8; ++j) s += bf2f(a.us[j]) * bf2f(b.us[j]);
    for (int off = 1; off < 64; off <<= 1) s += __shfl_xor(s, off);
    if (lane == 0) tout[row] = s;
}

// ---------------- fused logits + fixed-max softmax sums + masked denom ----------------
// m97 shape: grid (32,32); block 128x128, 2x2 waves, wave tile 64x64 via LDS a[4]/b[4]
// fragments (0.5 ds_reads/MFMA) with NO register-resident A (R4/R7: VGPR>128 ->
// <=3 waves/SIMD -> latency-starved). Target ~120 VGPR -> 4 waves/SIMD, 32 KB LDS
// -> 4 blocks/CU. BK=64 -> 8 long staging rounds (R6's failure: 32 tiny rounds).
// Fixed max M = alpha (|logit| <= alpha, L2-normalized inputs) -> per-lane accumulation.
__global__ __launch_bounds__(256) void flash_pass(
    const unsigned short* __restrict__ img, const unsigned short* __restrict__ txt,
    const int* __restrict__ labels, const float* __restrict__ tvals,
    const float* __restrict__ ls,
    float* __restrict__ lP, float* __restrict__ dP) {
    __shared__ __align__(16) unsigned short As[2 * 128 * 32];  // 16 KB [kc2][row][32k swz]
    __shared__ __align__(16) unsigned short Bs[2 * 128 * 32];  // 16 KB
    int tid = threadIdx.x;
    int wave = tid >> 6, lane = tid & 63;
    int wm = wave >> 1, wn = wave & 1;
    int q = lane >> 4, r = lane & 15;
    int row0 = blockIdx.x * 128, col0 = blockIdx.y * 128;
    float c1 = expf(ls[0]) * LOG2E;    // p = exp2(c1*(cos - 1)) = e^{s - M}, M = alpha
    int sw = (r >> 1) & 3;

    const unsigned short* gA[4]; const unsigned short* gB[4];
    unsigned short* lA[4]; unsigned short* lB[4];
    for (int i = 0; i < 4; ++i) {
        int u = i * 256 + tid;
        int kc2 = u >> 9, row = (u >> 2) & 127, kq = u & 3;
        int kq2 = kq ^ ((row >> 1) & 3);
        gA[i] = &img[(size_t)(row0 + row) * 512 + kc2 * 32 + kq2 * 8];
        gB[i] = &txt[(size_t)(col0 + row) * 512 + kc2 * 32 + kq2 * 8];
        lA[i] = &As[u * 8];
        lB[i] = &Bs[u * 8];
    }

    float4v acc[4][4];
    #pragma unroll
    for (int i = 0; i < 4; ++i)
        #pragma unroll
        for (int t = 0; t < 4; ++t) acc[i][t] = (float4v){0.f, 0.f, 0.f, 0.f};

    for (int it = 0; it < 8; ++it) {
        int k0 = it * 64;
        __syncthreads();
        #pragma unroll
        for (int i = 0; i < 4; ++i) {
            gl2lds16(gA[i] + k0, lA[i]);
            gl2lds16(gB[i] + k0, lB[i]);
        }
        __syncthreads();
        #pragma unroll
        for (int kc2 = 0; kc2 < 2; ++kc2) {
            short8 a0 = *(const short8*)&As[kc2 * 4096 + (wm * 64 +  0 + r) * 32 + (q ^ sw) * 8];
            short8 a1 = *(const short8*)&As[kc2 * 4096 + (wm * 64 + 16 + r) * 32 + (q ^ sw) * 8];
            short8 a2 = *(const short8*)&As[kc2 * 4096 + (wm * 64 + 32 + r) * 32 + (q ^ sw) * 8];
            short8 a3 = *(const short8*)&As[kc2 * 4096 + (wm * 64 + 48 + r) * 32 + (q ^ sw) * 8];
            #pragma unroll
            for (int t = 0; t < 4; ++t) {
                short8 b = *(const short8*)&Bs[kc2 * 4096 + (wn * 64 + t * 16 + r) * 32 + (q ^ sw) * 8];
                acc[0][t] = __builtin_amdgcn_mfma_f32_16x16x32_bf16(a0, b, acc[0][t], 0, 0, 0);
                acc[1][t] = __builtin_amdgcn_mfma_f32_16x16x32_bf16(a1, b, acc[1][t], 0, 0, 0);
                acc[2][t] = __builtin_amdgcn_mfma_f32_16x16x32_bf16(a2, b, acc[2][t], 0, 0, 0);
                acc[3][t] = __builtin_amdgcn_mfma_f32_16x16x32_bf16(a3, b, acc[3][t], 0, 0, 0);
            }
        }
    }

    // epilogue: per-row masked softmax partials for this wave's 64-col split
    int lc[4];
    #pragma unroll
    for (int t = 0; t < 4; ++t) lc[t] = labels[col0 + wn * 64 + t * 16 + r];
    int split = blockIdx.y * 2 + wn;
    #pragma unroll
    for (int i = 0; i < 4; ++i) {
        #pragma unroll
        for (int g = 0; g < 4; ++g) {
            int rw = row0 + wm * 64 + i * 16 + q * 4 + g;
            int lr = labels[rw];
            float tv = tvals[rw];
            float pl = 0.f, pd = 0.f;
            #pragma unroll
            for (int t = 0; t < 4; ++t) {
                float av = acc[i][t][g];
                float p = exp2f(fmaf(av, c1, -c1));
                pl += p;
                pd += ((av > tv) && (lc[t] != lr)) ? p : 0.f;
            }
            for (int off = 1; off < 16; off <<= 1) {
                pl += __shfl_xor(pl, off);
                pd += __shfl_xor(pd, off);
            }
            if (r == 0) {
                lP[(size_t)split * BATCH + rw] = pl;
                dP[(size_t)split * BATCH + rw] = pd;
            }
        }
    }
}

// ---------------- merge splits + per-row losses + global sum (atomic) ----------------
__global__ void combine(const float* __restrict__ lP, const float* __restrict__ dP,
                        const float* __restrict__ tvals, const float* __restrict__ ls,
                        float* __restrict__ out) {
    int row = blockIdx.x * 256 + threadIdx.x;
    float alpha = expf(ls[0]);
    float L = 0.f, D = 0.f;
    for (int s = 0; s < NSPLIT; ++s) {
        L += lP[(size_t)s * BATCH + row];
        D += dP[(size_t)s * BATCH + row];
    }
    float tm = alpha * (tvals[row] - 1.0f);   // t - M, with M = alpha
    float clip = logf(L) - tm;
    float py = expf(tm) / L;
    float cmp = (D > 0.f) ? py / (D / L + 1e-10f) : 0.f;
    float v = clip + cmp;
    for (int off = 1; off < 64; off <<= 1) v += __shfl_xor(v, off);
    __shared__ float w4[4];
    int wave = threadIdx.x >> 6, lane = threadIdx.x & 63;
    if (lane == 0) w4[wave] = v;
    __syncthreads();
    if (threadIdx.x == 0)
        atomicAdd(out, (w4[0] + w4[1] + w4[2] + w4[3]) * (1.0f / BATCH));
}

extern "C" void kernel_launch(void* const* d_in, const int* in_sizes, int n_in,
                              void* d_out, int out_size, void* d_ws, size_t ws_size,
                              hipStream_t stream) {
    const float* images = (const float*)d_in[0];
    const float* texts  = (const float*)d_in[1];
    const int*   labels = (const int*)d_in[2];
    const float* W_img  = (const float*)d_in[3];
    const float* W_txt  = (const float*)d_in[4];
    const float* lscale = (const float*)d_in[5];
    float* out = (float*)d_out;

    char* ws = (char*)d_ws;
    unsigned short* img_bf = (unsigned short*)(ws + 0);           // 6,291,456 B
    unsigned short* txt_bf = (unsigned short*)(ws + 6291456);     // 6,291,456 B
    unsigned short* wt_img = (unsigned short*)(ws + 12582912);    //   786,432 B
    unsigned short* wt_txt = (unsigned short*)(ws + 13369344);    //   786,432 B
    unsigned short* proj_i = (unsigned short*)(ws + 14155776);    // 4,194,304 B (bf16 img_n)
    unsigned short* proj_t = (unsigned short*)(ws + 18350080);    // 4,194,304 B (bf16 txt_n)
    // aliased over dead img_bf/txt_bf region (written only after the fused gemm):
    float*          lP     = (float*)(ws + 0);                    // 1,048,576 B
    float*          dP     = (float*)(ws + 1048576);              // 1,048,576 B
    float*          tvals  = (float*)(ws + 2097152);              //    16,384 B

    hipMemsetAsync(out, 0, sizeof(float), stream);
    prep<<<6912, 256, 0, stream>>>(images, texts, W_img, W_txt, img_bf, txt_bf, wt_img, wt_txt);
    gemm_nt<<<dim3(BATCH / 128, EDIM / 64, 2), 256, 0, stream>>>(img_bf, txt_bf, wt_img, wt_txt,
                                                                 proj_i, proj_t);
    norm_rows<<<dim3(BATCH / 4, 2), 256, 0, stream>>>(proj_i, proj_t);
    tdot<<<BATCH / 4, 256, 0, stream>>>(proj_i, proj_t, labels, tvals);
    flash_pass<<<dim3(BATCH / 128, BATCH / 128), 256, 0, stream>>>(proj_i, proj_t, labels, tvals,
                                                                   lscale, lP, dP);
    combine<<<16, 256, 0, stream>>>(lP, dP, tvals, lscale, out);
}